// Round 1
// baseline (396.335 us; speedup 1.0000x reference)
//
#include <hip/hip_runtime.h>
#include <math.h>

// Problem constants (fixed by reference setup_inputs)
constexpr int B  = 8;
constexpr int C  = 256;
constexpr int T  = 16;
constexpr int HW = 32 * 32;   // 1024
constexpr int Cr = 16;        // C / 16

// ---------------------------------------------------------------------------
// Kernel 1: one block per (b,c). Computes:
//   sp[bc, hw] = mean over t   (1024 outputs per block)
//   tp[bc, t]  = mean over hw  (16 outputs)
//   cp[bc]     = mean over t,hw (1 output)
// float4 loads: thread tid covers hw positions [4*tid, 4*tid+3].
// ---------------------------------------------------------------------------
__global__ __launch_bounds__(256) void pool_kernel(
    const float* __restrict__ x,
    float* __restrict__ sp, float* __restrict__ tp, float* __restrict__ cp)
{
    const int bc  = blockIdx.x;           // 0 .. B*C-1
    const int tid = threadIdx.x;          // 0 .. 255
    const int wave = tid >> 6, lane = tid & 63;

    const float4* xr = (const float4*)(x + (size_t)bc * T * HW);

    __shared__ float ltp[T][4];           // per-wave partial sums per t

    float4 acc = make_float4(0.f, 0.f, 0.f, 0.f);

    #pragma unroll
    for (int t = 0; t < T; ++t) {
        float4 v = xr[t * (HW / 4) + tid];
        acc.x += v.x; acc.y += v.y; acc.z += v.z; acc.w += v.w;
        float ts = v.x + v.y + v.z + v.w;
        // wave(64)-reduce
        #pragma unroll
        for (int off = 32; off > 0; off >>= 1)
            ts += __shfl_down(ts, off, 64);
        if (lane == 0) ltp[t][wave] = ts;
    }

    // spatial pool (mean over T)
    float4 spv = make_float4(acc.x / (float)T, acc.y / (float)T,
                             acc.z / (float)T, acc.w / (float)T);
    ((float4*)(sp + (size_t)bc * HW))[tid] = spv;

    __syncthreads();
    if (tid < T) {
        float s = ltp[tid][0] + ltp[tid][1] + ltp[tid][2] + ltp[tid][3];
        tp[bc * T + tid] = s / (float)HW;
        ltp[tid][0] = s;                  // stash full-t sum for cp
    }
    __syncthreads();
    if (tid == 0) {
        float s = 0.f;
        #pragma unroll
        for (int t = 0; t < T; ++t) s += ltp[t][0];
        cp[bc] = s / (float)(T * HW);
    }
}

// ---------------------------------------------------------------------------
// Kernel 2: fused SE for all three branches. One thread per pooled position
// (b, p); pooled layout is pooled[(b*C + c)*P + p] for P in {1024, 16, 1}.
// Each thread: h[16] = relu(W1 @ v + b1); att = sigmoid(W2 @ h + b2),
// written back IN PLACE (each thread owns a disjoint column).
// Blocks 0..31 -> spatial (8192 positions), 32 -> temporal (128), 33 -> channel (8).
// ---------------------------------------------------------------------------
__global__ __launch_bounds__(256) void se_kernel(
    float* __restrict__ sp, float* __restrict__ tp, float* __restrict__ cp,
    const float* __restrict__ ws1, const float* __restrict__ bs1,
    const float* __restrict__ ws2, const float* __restrict__ bs2,
    const float* __restrict__ wt1, const float* __restrict__ bt1,
    const float* __restrict__ wt2, const float* __restrict__ bt2,
    const float* __restrict__ wc1, const float* __restrict__ bc1,
    const float* __restrict__ wc2, const float* __restrict__ bc2)
{
    const int blk = blockIdx.x;

    float* pooled;
    const float *w1, *b1, *w2, *b2;
    int P, npos, base_pos;
    if (blk < 32) {
        pooled = sp; w1 = ws1; b1 = bs1; w2 = ws2; b2 = bs2;
        P = HW; npos = B * HW; base_pos = blk * 256;
    } else if (blk == 32) {
        pooled = tp; w1 = wt1; b1 = bt1; w2 = wt2; b2 = bt2;
        P = T; npos = B * T; base_pos = 0;
    } else {
        pooled = cp; w1 = wc1; b1 = bc1; w2 = wc2; b2 = bc2;
        P = 1; npos = B; base_pos = 0;
    }

    __shared__ float l1[Cr * C];   // w1[r][c]
    __shared__ float l2[C * Cr];   // w2[c][r]
    for (int i = threadIdx.x; i < Cr * C; i += 256) {
        l1[i] = w1[i];
        l2[i] = w2[i];
    }
    __syncthreads();

    const int gp = base_pos + threadIdx.x;
    if (gp >= npos) return;
    const int b = gp / P;
    const int p = gp - b * P;

    float* col = pooled + (size_t)b * C * P + p;

    float h[Cr];
    #pragma unroll
    for (int r = 0; r < Cr; ++r) h[r] = 0.f;

    for (int c = 0; c < C; ++c) {
        float v = col[(size_t)c * P];
        #pragma unroll
        for (int r = 0; r < Cr; ++r) h[r] += l1[r * C + c] * v;
    }
    #pragma unroll
    for (int r = 0; r < Cr; ++r) {
        float hv = h[r] + b1[r];
        h[r] = hv > 0.f ? hv : 0.f;
    }
    for (int c = 0; c < C; ++c) {
        float a = b2[c];
        #pragma unroll
        for (int r = 0; r < Cr; ++r) a += l2[c * Cr + r] * h[r];
        col[(size_t)c * P] = 1.f / (1.f + expf(-a));
    }
}

// ---------------------------------------------------------------------------
// Kernel 3: out = x * s_att * t_att * c_att, float4 in/out.
// One block per (b,c,t) row of 1024 elements; thread tid handles one float4.
// ---------------------------------------------------------------------------
__global__ __launch_bounds__(256) void apply_kernel(
    const float* __restrict__ x,
    const float* __restrict__ sp, const float* __restrict__ tp,
    const float* __restrict__ cp, float* __restrict__ out)
{
    const int blk = blockIdx.x;          // bc*T + t
    const int t   = blk & (T - 1);
    const int bc  = blk >> 4;
    const int tid = threadIdx.x;

    const size_t xoff = (size_t)blk * HW;
    const float4* xr   = (const float4*)(x + xoff);
    float4*       outr = (float4*)(out + xoff);
    const float4* sr   = (const float4*)(sp + (size_t)bc * HW);

    const float m = tp[bc * T + t] * cp[bc];

    float4 xv = xr[tid];
    float4 sv = sr[tid];
    float4 o;
    o.x = xv.x * sv.x * m;
    o.y = xv.y * sv.y * m;
    o.z = xv.z * sv.z * m;
    o.w = xv.w * sv.w * m;
    outr[tid] = o;
}

// ---------------------------------------------------------------------------
extern "C" void kernel_launch(void* const* d_in, const int* in_sizes, int n_in,
                              void* d_out, int out_size, void* d_ws, size_t ws_size,
                              hipStream_t stream)
{
    const float* x   = (const float*)d_in[0];
    const float* ws1 = (const float*)d_in[1];
    const float* bs1 = (const float*)d_in[2];
    const float* ws2 = (const float*)d_in[3];
    const float* bs2 = (const float*)d_in[4];
    const float* wt1 = (const float*)d_in[5];
    const float* bt1 = (const float*)d_in[6];
    const float* wt2 = (const float*)d_in[7];
    const float* bt2 = (const float*)d_in[8];
    const float* wc1 = (const float*)d_in[9];
    const float* bc1 = (const float*)d_in[10];
    const float* wc2 = (const float*)d_in[11];
    const float* bc2 = (const float*)d_in[12];
    float* out = (float*)d_out;

    // Workspace layout (floats): sp[B*C*HW] | tp[B*C*T] | cp[B*C]  (~8.5 MB)
    float* sp = (float*)d_ws;
    float* tp = sp + (size_t)B * C * HW;
    float* cp = tp + (size_t)B * C * T;

    pool_kernel<<<B * C, 256, 0, stream>>>(x, sp, tp, cp);
    se_kernel<<<34, 256, 0, stream>>>(sp, tp, cp,
                                      ws1, bs1, ws2, bs2,
                                      wt1, bt1, wt2, bt2,
                                      wc1, bc1, wc2, bc2);
    apply_kernel<<<B * C * T, 256, 0, stream>>>(x, sp, tp, cp, out);
}

// Round 2
// 307.215 us; speedup vs baseline: 1.2901x; 1.2901x over previous
//
#include <hip/hip_runtime.h>
#include <math.h>

constexpr int B  = 8;
constexpr int C  = 256;
constexpr int T  = 16;
constexpr int HW = 32 * 32;
constexpr int Cr = 16;

__global__ __launch_bounds__(256) void pool_kernel(
    const float* __restrict__ x,
    float* __restrict__ sp, float* __restrict__ tp, float* __restrict__ cp)
{
    const int bc  = blockIdx.x;
    const int tid = threadIdx.x;
    const int wave = tid >> 6, lane = tid & 63;

    const float4* xr = (const float4*)(x + (size_t)bc * T * HW);

    __shared__ float ltp[T][4];

    float4 acc = make_float4(0.f, 0.f, 0.f, 0.f);

    #pragma unroll
    for (int t = 0; t < T; ++t) {
        float4 v = xr[t * (HW / 4) + tid];
        acc.x += v.x; acc.y += v.y; acc.z += v.z; acc.w += v.w;
        float ts = v.x + v.y + v.z + v.w;
        #pragma unroll
        for (int off = 32; off > 0; off >>= 1)
            ts += __shfl_down(ts, off, 64);
        if (lane == 0) ltp[t][wave] = ts;
    }

    float4 spv = make_float4(acc.x / (float)T, acc.y / (float)T,
                             acc.z / (float)T, acc.w / (float)T);
    ((float4*)(sp + (size_t)bc * HW))[tid] = spv;

    __syncthreads();
    if (tid < T) {
        float s = ltp[tid][0] + ltp[tid][1] + ltp[tid][2] + ltp[tid][3];
        tp[bc * T + tid] = s / (float)HW;
        ltp[tid][0] = s;
    }
    __syncthreads();
    if (tid == 0) {
        float s = 0.f;
        #pragma unroll
        for (int t = 0; t < T; ++t) s += ltp[t][0];
        cp[bc] = s / (float)(T * HW);
    }
}

__device__ __forceinline__ float sigmoidf_(float a) {
    return 1.f / (1.f + __expf(-a));
}

__global__ __launch_bounds__(256) void se_kernel(
    float* __restrict__ sp, float* __restrict__ tp, float* __restrict__ cp,
    const float* __restrict__ ws1, const float* __restrict__ bs1,
    const float* __restrict__ ws2, const float* __restrict__ bs2,
    const float* __restrict__ wt1, const float* __restrict__ bt1,
    const float* __restrict__ wt2, const float* __restrict__ bt2,
    const float* __restrict__ wc1, const float* __restrict__ bc1,
    const float* __restrict__ wc2, const float* __restrict__ bc2)
{
    __shared__ float l1[Cr * C];
    __shared__ float l2[C * Cr];
    __shared__ float b1l[Cr];
    __shared__ float b2l[C];
    __shared__ float hred[4096];
    __shared__ float hf[Cr * 64];

    const int blk = blockIdx.x;
    const int tid = threadIdx.x;

    const float *w1, *bb1, *w2, *bb2;
    if (blk < 128)      { w1 = ws1; bb1 = bs1; w2 = ws2; bb2 = bs2; }
    else if (blk < 136) { w1 = wt1; bb1 = bt1; w2 = wt2; bb2 = bt2; }
    else                { w1 = wc1; bb1 = bc1; w2 = wc2; bb2 = bc2; }

    for (int i = tid; i < Cr * C; i += 256) { l1[i] = w1[i]; l2[i] = w2[i]; }
    if (tid < Cr) b1l[tid] = bb1[tid];
    b2l[tid] = bb2[tid];
    __syncthreads();

    if (blk < 128) {
        // ----- spatial: b = blk>>4, ptile = (blk&15)*64 -----
        const int b = blk >> 4;
        const int ptile = (blk & 15) * 64;
        const int p = tid & 63, cg = tid >> 6;
        float* base = sp + (size_t)b * C * HW + ptile + p;

        float h[Cr];
        #pragma unroll
        for (int r = 0; r < Cr; ++r) h[r] = 0.f;

        #pragma unroll 8
        for (int cc = 0; cc < 64; ++cc) {
            const int c = cg * 64 + cc;
            float v = base[(size_t)c * HW];
            #pragma unroll
            for (int r = 0; r < Cr; ++r) h[r] += l1[r * C + c] * v;
        }
        #pragma unroll
        for (int r = 0; r < Cr; ++r) hred[(r * 4 + cg) * 64 + p] = h[r];
        __syncthreads();

        {
            const int r0 = (tid >> 6) * 4, pp = tid & 63;
            #pragma unroll
            for (int rr = 0; rr < 4; ++rr) {
                const int r = r0 + rr;
                float s = hred[(r * 4 + 0) * 64 + pp] + hred[(r * 4 + 1) * 64 + pp]
                        + hred[(r * 4 + 2) * 64 + pp] + hred[(r * 4 + 3) * 64 + pp];
                s += b1l[r];
                hf[r * 64 + pp] = s > 0.f ? s : 0.f;
            }
        }
        __syncthreads();

        float hr[Cr];
        #pragma unroll
        for (int r = 0; r < Cr; ++r) hr[r] = hf[r * 64 + p];

        const int c0 = cg * 64;
        #pragma unroll 4
        for (int cc = 0; cc < 64; ++cc) {
            const int c = c0 + cc;
            float a = b2l[c];
            #pragma unroll
            for (int r = 0; r < Cr; ++r) a += l2[c * Cr + r] * hr[r];
            base[(size_t)c * HW] = sigmoidf_(a);
        }
    } else if (blk < 136) {
        // ----- temporal -----
        const int b = blk - 128;
        float* base = tp + (size_t)b * C * T;
        const int t = tid & 15, cg = tid >> 4;

        float h[Cr];
        #pragma unroll
        for (int r = 0; r < Cr; ++r) h[r] = 0.f;

        #pragma unroll
        for (int cc = 0; cc < 16; ++cc) {
            const int c = cg * 16 + cc;
            float v = base[c * T + t];
            #pragma unroll
            for (int r = 0; r < Cr; ++r) h[r] += l1[r * C + c] * v;
        }
        #pragma unroll
        for (int r = 0; r < Cr; ++r) hred[(r * 16 + cg) * 16 + t] = h[r];
        __syncthreads();

        {
            const int r = tid >> 4, tt = tid & 15;
            float s = b1l[r];
            #pragma unroll
            for (int g = 0; g < 16; ++g) s += hred[(r * 16 + g) * 16 + tt];
            hf[r * 16 + tt] = s > 0.f ? s : 0.f;
        }
        __syncthreads();

        {
            const int c = tid;
            float acc[T];
            #pragma unroll
            for (int tt = 0; tt < T; ++tt) acc[tt] = b2l[c];
            #pragma unroll
            for (int r = 0; r < Cr; ++r) {
                const float w = l2[c * Cr + r];
                #pragma unroll
                for (int tt = 0; tt < T; ++tt) acc[tt] += w * hf[r * 16 + tt];
            }
            #pragma unroll
            for (int tt = 0; tt < T; ++tt) base[c * T + tt] = sigmoidf_(acc[tt]);
        }
    } else {
        // ----- channel -----
        const int b8 = tid >> 5, cg = tid & 31;

        float h[Cr];
        #pragma unroll
        for (int r = 0; r < Cr; ++r) h[r] = 0.f;

        #pragma unroll
        for (int cc = 0; cc < 8; ++cc) {
            const int c = cg * 8 + cc;
            float v = cp[b8 * C + c];
            #pragma unroll
            for (int r = 0; r < Cr; ++r) h[r] += l1[r * C + c] * v;
        }
        #pragma unroll
        for (int r = 0; r < Cr; ++r) hred[(r * 8 + b8) * 32 + cg] = h[r];
        __syncthreads();

        if (tid < 128) {
            const int b = tid >> 4, r = tid & 15;
            float s = b1l[r];
            #pragma unroll
            for (int g = 0; g < 32; ++g) s += hred[(r * 8 + b) * 32 + g];
            hf[b * Cr + r] = s > 0.f ? s : 0.f;
        }
        __syncthreads();

        {
            const int c = tid;
            #pragma unroll
            for (int b = 0; b < B; ++b) {
                float a = b2l[c];
                #pragma unroll
                for (int r = 0; r < Cr; ++r) a += l2[c * Cr + r] * hf[b * Cr + r];
                cp[b * C + c] = sigmoidf_(a);
            }
        }
    }
}

__global__ __launch_bounds__(256) void apply_kernel(
    const float* __restrict__ x,
    const float* __restrict__ sp, const float* __restrict__ tp,
    const float* __restrict__ cp, float* __restrict__ out)
{
    const int bc  = blockIdx.x;
    const int tid = threadIdx.x;

    const size_t xoff = (size_t)bc * T * HW;
    const float4* xr   = (const float4*)(x + xoff);
    float4*       outr = (float4*)(out + xoff);

    const float4 sv = ((const float4*)(sp + (size_t)bc * HW))[tid];
    const float  cm = cp[bc];

    #pragma unroll
    for (int t = 0; t < T; ++t) {
        const float m = tp[bc * T + t] * cm;
        float4 xv = xr[t * (HW / 4) + tid];
        float4 o;
        o.x = xv.x * sv.x * m;
        o.y = xv.y * sv.y * m;
        o.z = xv.z * sv.z * m;
        o.w = xv.w * sv.w * m;
        outr[t * (HW / 4) + tid] = o;
    }
}

extern "C" void kernel_launch(void* const* d_in, const int* in_sizes, int n_in,
                              void* d_out, int out_size, void* d_ws, size_t ws_size,
                              hipStream_t stream)
{
    const float* x   = (const float*)d_in[0];
    const float* ws1 = (const float*)d_in[1];
    const float* bs1 = (const float*)d_in[2];
    const float* ws2 = (const float*)d_in[3];
    const float* bs2 = (const float*)d_in[4];
    const float* wt1 = (const float*)d_in[5];
    const float* bt1 = (const float*)d_in[6];
    const float* wt2 = (const float*)d_in[7];
    const float* bt2 = (const float*)d_in[8];
    const float* wc1 = (const float*)d_in[9];
    const float* bc1 = (const float*)d_in[10];
    const float* wc2 = (const float*)d_in[11];
    const float* bc2 = (const float*)d_in[12];
    float* out = (float*)d_out;

    float* sp = (float*)d_ws;
    float* tp = sp + (size_t)B * C * HW;
    float* cp = tp + (size_t)B * C * T;

    pool_kernel<<<B * C, 256, 0, stream>>>(x, sp, tp, cp);
    se_kernel<<<137, 256, 0, stream>>>(sp, tp, cp,
                                       ws1, bs1, ws2, bs2,
                                       wt1, bt1, wt2, bt2,
                                       wc1, bc1, wc2, bc2);
    apply_kernel<<<B * C, 256, 0, stream>>>(x, sp, tp, cp, out);
}

// Round 5
// 305.794 us; speedup vs baseline: 1.2961x; 1.0046x over previous
//
#include <hip/hip_runtime.h>
#include <math.h>

constexpr int B  = 8;
constexpr int C  = 256;
constexpr int T  = 16;
constexpr int HW = 32 * 32;   // 1024
constexpr int Cr = 16;        // C / 16

typedef float vfloat4 __attribute__((ext_vector_type(4)));

// ---------------------------------------------------------------------------
// Kernel 1: one block per (b,c). sp = mean over T, tp = mean over HW,
// cp = mean over all. float4 loads, wave-64 shuffle reduce.
// ---------------------------------------------------------------------------
__global__ __launch_bounds__(256) void pool_kernel(
    const float* __restrict__ x,
    float* __restrict__ sp, float* __restrict__ tp, float* __restrict__ cp)
{
    const int bc  = blockIdx.x;
    const int tid = threadIdx.x;
    const int wave = tid >> 6, lane = tid & 63;

    const float4* xr = (const float4*)(x + (size_t)bc * T * HW);

    __shared__ float ltp[T][4];

    float4 acc = make_float4(0.f, 0.f, 0.f, 0.f);

    #pragma unroll
    for (int t = 0; t < T; ++t) {
        float4 v = xr[t * (HW / 4) + tid];
        acc.x += v.x; acc.y += v.y; acc.z += v.z; acc.w += v.w;
        float ts = v.x + v.y + v.z + v.w;
        #pragma unroll
        for (int off = 32; off > 0; off >>= 1)
            ts += __shfl_down(ts, off, 64);
        if (lane == 0) ltp[t][wave] = ts;
    }

    float4 spv = make_float4(acc.x / (float)T, acc.y / (float)T,
                             acc.z / (float)T, acc.w / (float)T);
    ((float4*)(sp + (size_t)bc * HW))[tid] = spv;

    __syncthreads();
    if (tid < T) {
        float s = ltp[tid][0] + ltp[tid][1] + ltp[tid][2] + ltp[tid][3];
        tp[bc * T + tid] = s / (float)HW;
        ltp[tid][0] = s;
    }
    __syncthreads();
    if (tid == 0) {
        float s = 0.f;
        #pragma unroll
        for (int t = 0; t < T; ++t) s += ltp[t][0];
        cp[bc] = s / (float)(T * HW);
    }
}

__device__ __forceinline__ float sigmoidf_(float a) {
    return 1.f / (1.f + __expf(-a));
}

// ---------------------------------------------------------------------------
// Kernel 2: fused SE for the three branches, attention in place.
// blocks 0..127 spatial, 128..135 temporal, 136 channel.
// ---------------------------------------------------------------------------
__global__ __launch_bounds__(256) void se_kernel(
    float* __restrict__ sp, float* __restrict__ tp, float* __restrict__ cp,
    const float* __restrict__ ws1, const float* __restrict__ bs1,
    const float* __restrict__ ws2, const float* __restrict__ bs2,
    const float* __restrict__ wt1, const float* __restrict__ bt1,
    const float* __restrict__ wt2, const float* __restrict__ bt2,
    const float* __restrict__ wc1, const float* __restrict__ bc1,
    const float* __restrict__ wc2, const float* __restrict__ bc2)
{
    __shared__ float l1[Cr * C];
    __shared__ float l2[C * Cr];
    __shared__ float b1l[Cr];
    __shared__ float b2l[C];
    __shared__ float hred[4096];
    __shared__ float hf[Cr * 64];

    const int blk = blockIdx.x;
    const int tid = threadIdx.x;

    const float *w1, *bb1, *w2, *bb2;
    if (blk < 128)      { w1 = ws1; bb1 = bs1; w2 = ws2; bb2 = bs2; }
    else if (blk < 136) { w1 = wt1; bb1 = bt1; w2 = wt2; bb2 = bt2; }
    else                { w1 = wc1; bb1 = bc1; w2 = wc2; bb2 = bc2; }

    for (int i = tid; i < Cr * C; i += 256) { l1[i] = w1[i]; l2[i] = w2[i]; }
    if (tid < Cr) b1l[tid] = bb1[tid];
    b2l[tid] = bb2[tid];
    __syncthreads();

    if (blk < 128) {
        // spatial: b = blk>>4, ptile = (blk&15)*64
        const int b = blk >> 4;
        const int ptile = (blk & 15) * 64;
        const int p = tid & 63, cg = tid >> 6;
        float* base = sp + (size_t)b * C * HW + ptile + p;

        float h[Cr];
        #pragma unroll
        for (int r = 0; r < Cr; ++r) h[r] = 0.f;

        #pragma unroll 8
        for (int cc = 0; cc < 64; ++cc) {
            const int c = cg * 64 + cc;
            float v = base[(size_t)c * HW];
            #pragma unroll
            for (int r = 0; r < Cr; ++r) h[r] += l1[r * C + c] * v;
        }
        #pragma unroll
        for (int r = 0; r < Cr; ++r) hred[(r * 4 + cg) * 64 + p] = h[r];
        __syncthreads();

        {
            const int r0 = (tid >> 6) * 4, pp = tid & 63;
            #pragma unroll
            for (int rr = 0; rr < 4; ++rr) {
                const int r = r0 + rr;
                float s = hred[(r * 4 + 0) * 64 + pp] + hred[(r * 4 + 1) * 64 + pp]
                        + hred[(r * 4 + 2) * 64 + pp] + hred[(r * 4 + 3) * 64 + pp];
                s += b1l[r];
                hf[r * 64 + pp] = s > 0.f ? s : 0.f;
            }
        }
        __syncthreads();

        float hr[Cr];
        #pragma unroll
        for (int r = 0; r < Cr; ++r) hr[r] = hf[r * 64 + p];

        const int c0 = cg * 64;
        #pragma unroll 4
        for (int cc = 0; cc < 64; ++cc) {
            const int c = c0 + cc;
            float a = b2l[c];
            #pragma unroll
            for (int r = 0; r < Cr; ++r) a += l2[c * Cr + r] * hr[r];
            base[(size_t)c * HW] = sigmoidf_(a);
        }
    } else if (blk < 136) {
        // temporal
        const int b = blk - 128;
        float* base = tp + (size_t)b * C * T;
        const int t = tid & 15, cg = tid >> 4;

        float h[Cr];
        #pragma unroll
        for (int r = 0; r < Cr; ++r) h[r] = 0.f;

        #pragma unroll
        for (int cc = 0; cc < 16; ++cc) {
            const int c = cg * 16 + cc;
            float v = base[c * T + t];
            #pragma unroll
            for (int r = 0; r < Cr; ++r) h[r] += l1[r * C + c] * v;
        }
        #pragma unroll
        for (int r = 0; r < Cr; ++r) hred[(r * 16 + cg) * 16 + t] = h[r];
        __syncthreads();

        {
            const int r = tid >> 4, tt = tid & 15;
            float s = b1l[r];
            #pragma unroll
            for (int g = 0; g < 16; ++g) s += hred[(r * 16 + g) * 16 + tt];
            hf[r * 16 + tt] = s > 0.f ? s : 0.f;
        }
        __syncthreads();

        {
            const int c = tid;
            float acc[T];
            #pragma unroll
            for (int tt = 0; tt < T; ++tt) acc[tt] = b2l[c];
            #pragma unroll
            for (int r = 0; r < Cr; ++r) {
                const float w = l2[c * Cr + r];
                #pragma unroll
                for (int tt = 0; tt < T; ++tt) acc[tt] += w * hf[r * 16 + tt];
            }
            #pragma unroll
            for (int tt = 0; tt < T; ++tt) base[c * T + tt] = sigmoidf_(acc[tt]);
        }
    } else {
        // channel
        const int b8 = tid >> 5, cg = tid & 31;

        float h[Cr];
        #pragma unroll
        for (int r = 0; r < Cr; ++r) h[r] = 0.f;

        #pragma unroll
        for (int cc = 0; cc < 8; ++cc) {
            const int c = cg * 8 + cc;
            float v = cp[b8 * C + c];
            #pragma unroll
            for (int r = 0; r < Cr; ++r) h[r] += l1[r * C + c] * v;
        }
        #pragma unroll
        for (int r = 0; r < Cr; ++r) hred[(r * 8 + b8) * 32 + cg] = h[r];
        __syncthreads();

        if (tid < 128) {
            const int b = tid >> 4, r = tid & 15;
            float s = b1l[r];
            #pragma unroll
            for (int g = 0; g < 32; ++g) s += hred[(r * 8 + b) * 32 + g];
            hf[b * Cr + r] = s > 0.f ? s : 0.f;
        }
        __syncthreads();

        {
            const int c = tid;
            #pragma unroll
            for (int b = 0; b < B; ++b) {
                float a = b2l[c];
                #pragma unroll
                for (int r = 0; r < Cr; ++r) a += l2[c * Cr + r] * hf[b * Cr + r];
                cp[b * C + c] = sigmoidf_(a);
            }
        }
    }
}

// ---------------------------------------------------------------------------
// Kernel 3: out = x * s_att * t_att * c_att. One block per (b,c).
// Nontemporal x load (last use) and out store (never re-read) via
// ext_vector_type float4 (HIP_vector_type is rejected by the builtin).
// ---------------------------------------------------------------------------
__global__ __launch_bounds__(256) void apply_kernel(
    const float* __restrict__ x,
    const float* __restrict__ sp, const float* __restrict__ tp,
    const float* __restrict__ cp, float* __restrict__ out)
{
    const int bc  = blockIdx.x;
    const int tid = threadIdx.x;

    const size_t xoff = (size_t)bc * T * HW;
    const vfloat4* xr   = (const vfloat4*)(x + xoff);
    vfloat4*       outr = (vfloat4*)(out + xoff);

    const float4 sv = ((const float4*)(sp + (size_t)bc * HW))[tid];
    const float  cm = cp[bc];

    #pragma unroll
    for (int t = 0; t < T; ++t) {
        const float m = tp[bc * T + t] * cm;
        vfloat4 xv = __builtin_nontemporal_load(&xr[t * (HW / 4) + tid]);
        vfloat4 o;
        o.x = xv.x * sv.x * m;
        o.y = xv.y * sv.y * m;
        o.z = xv.z * sv.z * m;
        o.w = xv.w * sv.w * m;
        __builtin_nontemporal_store(o, &outr[t * (HW / 4) + tid]);
    }
}

// ---------------------------------------------------------------------------
extern "C" void kernel_launch(void* const* d_in, const int* in_sizes, int n_in,
                              void* d_out, int out_size, void* d_ws, size_t ws_size,
                              hipStream_t stream)
{
    const float* x   = (const float*)d_in[0];
    const float* ws1 = (const float*)d_in[1];
    const float* bs1 = (const float*)d_in[2];
    const float* ws2 = (const float*)d_in[3];
    const float* bs2 = (const float*)d_in[4];
    const float* wt1 = (const float*)d_in[5];
    const float* bt1 = (const float*)d_in[6];
    const float* wt2 = (const float*)d_in[7];
    const float* bt2 = (const float*)d_in[8];
    const float* wc1 = (const float*)d_in[9];
    const float* bc1 = (const float*)d_in[10];
    const float* wc2 = (const float*)d_in[11];
    const float* bc2 = (const float*)d_in[12];
    float* out = (float*)d_out;

    float* sp = (float*)d_ws;
    float* tp = sp + (size_t)B * C * HW;
    float* cp = tp + (size_t)B * C * T;

    pool_kernel<<<B * C, 256, 0, stream>>>(x, sp, tp, cp);
    se_kernel<<<137, 256, 0, stream>>>(sp, tp, cp,
                                       ws1, bs1, ws2, bs2,
                                       wt1, bt1, wt2, bt2,
                                       wc1, bc1, wc2, bc2);
    apply_kernel<<<B * C, 256, 0, stream>>>(x, sp, tp, cp, out);
}